// Round 1
// baseline (7442.183 us; speedup 1.0000x reference)
//
#include <hip/hip_runtime.h>
#include <stdint.h>

// ---------------------------------------------------------------------------
// Conv-SNN, 100 steps, B=64. BETA=0 so LIF state is 1 bit (prev spike).
// Pipeline: threefry poisson spikes -> conv1+pool+LIF1 -> conv2+pool+LIF2
//           -> FC -> LIF3 (outputs spk + mem).
// All conv/dot accumulation in f64 (correctly-rounded truth), rounded to f32
// at the same op boundaries as the JAX reference.
// ---------------------------------------------------------------------------

#define NSTEPS 100
#define NB 64
#define N_SPK0 19660800   // 100*64*3*32*32
#define XSZ    196608     // 64*3*32*32

__device__ __forceinline__ uint32_t rotl32(uint32_t v, uint32_t r) {
  return (v << r) | (v >> (32u - r));
}

// Threefry-2x32, 20 rounds (Random123 / JAX schedule).
__device__ __forceinline__ void threefry2x32(uint32_t k0, uint32_t k1,
                                             uint32_t& x0, uint32_t& x1) {
  uint32_t k2 = k0 ^ k1 ^ 0x1BD11BDAu;
  x0 += k0; x1 += k1;
#define TF_R(r) { x0 += x1; x1 = rotl32(x1, r); x1 ^= x0; }
  TF_R(13u) TF_R(15u) TF_R(26u) TF_R(6u)
  x0 += k1; x1 += k2 + 1u;
  TF_R(17u) TF_R(29u) TF_R(16u) TF_R(24u)
  x0 += k2; x1 += k0 + 2u;
  TF_R(13u) TF_R(15u) TF_R(26u) TF_R(6u)
  x0 += k0; x1 += k1 + 3u;
  TF_R(17u) TF_R(29u) TF_R(16u) TF_R(24u)
  x0 += k1; x1 += k2 + 4u;
  TF_R(13u) TF_R(15u) TF_R(26u) TF_R(6u)
  x0 += k2; x1 += k0 + 5u;
#undef TF_R
}

// Kernel 0: poisson spike train. JAX partitionable threefry path:
// bits[i] = y0 ^ y1 of threefry(key=(0,1), counts=(hi=0, lo=i)).
// uniform = bitcast((bits>>9)|0x3f800000) - 1.0f; spike = (u < 2*x).
__global__ void gen_spikes(const float* __restrict__ x,
                           unsigned char* __restrict__ spk0) {
  int i = blockIdx.x * 256 + threadIdx.x;
  if (i >= N_SPK0) return;
  uint32_t x0 = 0u, x1 = (uint32_t)i;
  threefry2x32(0u, 1u, x0, x1);
  uint32_t bits = x0 ^ x1;
  float u = __uint_as_float((bits >> 9) | 0x3f800000u) - 1.0f;
  int r = i % XSZ;  // x index (b,c,h,w)
  spk0[i] = (u < 2.0f * x[r]) ? 1 : 0;
}

// Kernel 1: conv1(3->32,5x5 VALID on 32x32) + 2x2 avgpool + LIF1.
// One block per (b, oc); thread = pooled output (oh,ow) in 14x14.
// Effective 6x6 kernel Weff[c][iy][ix] folds the 2x2 pool window.
__global__ void conv1_lif(const unsigned char* __restrict__ spk0,
                          const float* __restrict__ W_in,
                          unsigned char* __restrict__ spk1) {
  const int b  = blockIdx.x;   // 0..63
  const int oc = blockIdx.y;   // 0..31
  __shared__ double sW[108];          // [3][6][6]
  __shared__ unsigned char sF[3072];  // [3][32][32]
  const int tid = threadIdx.x;        // 0..255 (196 compute)

  if (tid < 108) {
    int c = tid / 36, iy = (tid / 6) % 6, ix = tid % 6;
    double w = 0.0;
    for (int dy = 0; dy < 2; ++dy) {
      int ky = iy - dy; if (ky < 0 || ky > 4) continue;
      for (int dx = 0; dx < 2; ++dx) {
        int kx = ix - dx; if (kx < 0 || kx > 4) continue;
        w += (double)W_in[((oc * 3 + c) * 5 + ky) * 5 + kx];
      }
    }
    sW[tid] = w;
  }

  const int oh = tid / 14, ow = tid % 14;
  float prev = 0.0f;
  for (int t = 0; t < NSTEPS; ++t) {
    __syncthreads();  // covers sW at t=0, protects sF reuse afterwards
    const uint4* src = (const uint4*)(spk0 + (size_t)(t * NB + b) * 3072);
    if (tid < 192) ((uint4*)sF)[tid] = src[tid];
    __syncthreads();
    if (tid < 196) {
      double acc = 0.0;
      #pragma unroll
      for (int c = 0; c < 3; ++c) {
        #pragma unroll
        for (int iy = 0; iy < 6; ++iy) {
          const unsigned char* row = &sF[c * 1024 + (2 * oh + iy) * 32 + 2 * ow];
          const double* wr = &sW[c * 36 + iy * 6];
          #pragma unroll
          for (int ix = 0; ix < 6; ++ix) { if (row[ix]) acc += wr[ix]; }
        }
      }
      float cur = (float)(acc * 0.25);
      float mem = cur - prev;
      bool s = mem > 1.0f;
      spk1[((size_t)(t * NB + b) * 32 + oc) * 196 + tid] = s ? 1 : 0;
      prev = s ? 1.0f : 0.0f;
    }
  }
}

// Kernel 2: conv2(32->64,5x5 VALID on 14x14) + 2x2 avgpool + LIF2.
// Block per (oc, group of 8 b); 256 threads = 8 b x 32 (25 active outputs).
__global__ void conv2_lif(const unsigned char* __restrict__ spk1,
                          const float* __restrict__ W_h1,
                          unsigned char* __restrict__ spk2) {
  const int bg = blockIdx.x;   // 0..7  -> b0 = bg*8
  const int oc = blockIdx.y;   // 0..63
  __shared__ double sW[1152];           // [32][6][6]
  __shared__ unsigned char sF[50176];   // 8 x [32][14][14]
  const int tid = threadIdx.x;

  for (int e = tid; e < 1152; e += 256) {
    int c = e / 36, iy = (e / 6) % 6, ix = e % 6;
    double w = 0.0;
    for (int dy = 0; dy < 2; ++dy) {
      int ky = iy - dy; if (ky < 0 || ky > 4) continue;
      for (int dx = 0; dx < 2; ++dx) {
        int kx = ix - dx; if (kx < 0 || kx > 4) continue;
        w += (double)W_h1[((oc * 32 + c) * 5 + ky) * 5 + kx];
      }
    }
    sW[e] = w;
  }

  const int bi = tid >> 5;        // 0..7
  const int p  = tid & 31;        // 0..31 (<25 active)
  const int oh = p / 5, ow = p % 5;
  const int b0 = bg * 8;
  float prev = 0.0f;
  for (int t = 0; t < NSTEPS; ++t) {
    __syncthreads();
    // 8 consecutive batches are contiguous: one 50176B block copy
    const uint4* src = (const uint4*)(spk1 + (size_t)(t * NB + b0) * 6272);
    uint4* dst = (uint4*)sF;
    for (int j = tid; j < 3136; j += 256) dst[j] = src[j];
    __syncthreads();
    if (p < 25) {
      double acc = 0.0;
      const unsigned char* fb = &sF[bi * 6272];
      for (int c = 0; c < 32; ++c) {
        const unsigned char* ch = &fb[c * 196];
        const double* wc = &sW[c * 36];
        #pragma unroll
        for (int iy = 0; iy < 6; ++iy) {
          const unsigned char* row = &ch[(2 * oh + iy) * 14 + 2 * ow];
          const double* wr = &wc[iy * 6];
          #pragma unroll
          for (int ix = 0; ix < 6; ++ix) { if (row[ix]) acc += wr[ix]; }
        }
      }
      float cur = (float)(acc * 0.25);
      float mem = cur - prev;
      bool s = mem > 1.0f;
      spk2[((size_t)(t * NB + b0 + bi) * 64 + oc) * 25 + p] = s ? 1 : 0;
      prev = s ? 1.0f : 0.0f;
    }
  }
}

// Kernel 3: FC cur3[t,b,o] = sum_k spk2[t,b,k] * W_h2[o,k], k<1600.
__global__ void fc_kernel(const unsigned char* __restrict__ spk2,
                          const float* __restrict__ W2,
                          float* __restrict__ cur3) {
  int gid = blockIdx.x * 256 + threadIdx.x;
  if (gid >= NSTEPS * NB * 10) return;
  int tb = gid / 10, o = gid % 10;
  const unsigned char* s = spk2 + (size_t)tb * 1600;
  const float* w = W2 + o * 1600;
  double acc = 0.0;
  for (int k = 0; k < 1600; ++k) { if (s[k]) acc += (double)w[k]; }
  cur3[gid] = (float)acc;
}

// Kernel 4: LIF3 over t; writes out_spikes [100,64,10] then memh2 [100,64,10].
__global__ void lif3_kernel(const float* __restrict__ cur3,
                            float* __restrict__ out) {
  int bo = blockIdx.x * 256 + threadIdx.x;
  if (bo >= NB * 10) return;
  float prev = 0.0f;
  for (int t = 0; t < NSTEPS; ++t) {
    float cur = cur3[t * (NB * 10) + bo];
    float mem = cur - prev;
    bool s = mem > 1.0f;
    out[t * (NB * 10) + bo] = s ? 1.0f : 0.0f;
    out[NSTEPS * NB * 10 + t * (NB * 10) + bo] = mem;
    prev = s ? 1.0f : 0.0f;
  }
}

extern "C" void kernel_launch(void* const* d_in, const int* in_sizes, int n_in,
                              void* d_out, int out_size, void* d_ws, size_t ws_size,
                              hipStream_t stream) {
  const float* x    = (const float*)d_in[0];
  const float* W_in = (const float*)d_in[1];
  const float* W_h1 = (const float*)d_in[2];
  const float* W_h2 = (const float*)d_in[3];
  float* out = (float*)d_out;

  unsigned char* ws = (unsigned char*)d_ws;
  unsigned char* spk0 = ws;                      // 19,660,800 B
  unsigned char* spk1 = ws + 19660800;           // 40,140,800 B
  unsigned char* spk2 = ws + 59801600;           // 10,240,000 B
  float*         cur3 = (float*)(ws + 70041600); //    256,000 B

  gen_spikes<<<(N_SPK0 + 255) / 256, 256, 0, stream>>>(x, spk0);
  conv1_lif<<<dim3(64, 32), 256, 0, stream>>>(spk0, W_in, spk1);
  conv2_lif<<<dim3(8, 64), 256, 0, stream>>>(spk1, W_h1, spk2);
  fc_kernel<<<(NSTEPS * NB * 10 + 255) / 256, 256, 0, stream>>>(spk2, W_h2, cur3);
  lif3_kernel<<<3, 256, 0, stream>>>(cur3, out);
}

// Round 2
// 1386.724 us; speedup vs baseline: 5.3667x; 5.3667x over previous
//
#include <hip/hip_runtime.h>
#include <stdint.h>

// ---------------------------------------------------------------------------
// Conv-SNN, 100 steps, B=64, BETA=0.
// Round 2: t-parallel convs + bitpacked spikes + f64 FMA (4 oc per thread),
// LIF recurrences as separate elementwise scans. f64 internal, f32 at the
// same op boundaries as round 1 (which matched ref with absmax 0.0).
// ---------------------------------------------------------------------------

#define NSTEPS 100
#define NB 64

__device__ __forceinline__ uint32_t rotl32(uint32_t v, uint32_t r) {
  return (v << r) | (v >> (32u - r));
}

__device__ __forceinline__ void threefry2x32(uint32_t k0, uint32_t k1,
                                             uint32_t& x0, uint32_t& x1) {
  uint32_t k2 = k0 ^ k1 ^ 0x1BD11BDAu;
  x0 += k0; x1 += k1;
#define TF_R(r) { x0 += x1; x1 = rotl32(x1, r); x1 ^= x0; }
  TF_R(13u) TF_R(15u) TF_R(26u) TF_R(6u)
  x0 += k1; x1 += k2 + 1u;
  TF_R(17u) TF_R(29u) TF_R(16u) TF_R(24u)
  x0 += k2; x1 += k0 + 2u;
  TF_R(13u) TF_R(15u) TF_R(26u) TF_R(6u)
  x0 += k0; x1 += k1 + 3u;
  TF_R(17u) TF_R(29u) TF_R(16u) TF_R(24u)
  x0 += k1; x1 += k2 + 4u;
  TF_R(13u) TF_R(15u) TF_R(26u) TF_R(6u)
  x0 += k2; x1 += k0 + 5u;
#undef TF_R
}

// --- folded-pool weights (f64), conv1: Weff1[oc32][c3][pos36] -------------
__global__ __launch_bounds__(256) void weff1_kernel(const float* __restrict__ W_in,
                                                    double* __restrict__ Weff1) {
  int e = blockIdx.x * 256 + threadIdx.x;
  if (e >= 32 * 3 * 36) return;
  int pos = e % 36, c = (e / 36) % 3, oc = e / 108;
  int iy = pos / 6, ix = pos % 6;
  double w = 0.0;
  for (int dy = 0; dy < 2; ++dy) {
    int ky = iy - dy; if (ky < 0 || ky > 4) continue;
    for (int dx = 0; dx < 2; ++dx) {
      int kx = ix - dx; if (kx < 0 || kx > 4) continue;
      w += (double)W_in[((oc * 3 + c) * 5 + ky) * 5 + kx];
    }
  }
  Weff1[e] = w;
}

// conv2: Weff2[og16][c32][pos36][oj4], oc = og*4+oj
__global__ __launch_bounds__(256) void weff2_kernel(const float* __restrict__ W_h1,
                                                    double* __restrict__ Weff2) {
  int e = blockIdx.x * 256 + threadIdx.x;
  if (e >= 16 * 32 * 36 * 4) return;
  int oj = e & 3, pos = (e >> 2) % 36, c = (e >> 2) / 36 % 32, og = e / (4 * 36 * 32);
  int oc = og * 4 + oj;
  int iy = pos / 6, ix = pos % 6;
  double w = 0.0;
  for (int dy = 0; dy < 2; ++dy) {
    int ky = iy - dy; if (ky < 0 || ky > 4) continue;
    for (int dx = 0; dx < 2; ++dx) {
      int kx = ix - dx; if (kx < 0 || kx > 4) continue;
      w += (double)W_h1[((oc * 32 + c) * 5 + ky) * 5 + kx];
    }
  }
  Weff2[e] = w;
}

// --- spike gen: per-pixel 3-bit channel codes [t,b,1024] bytes ------------
__global__ __launch_bounds__(256) void gen_spikes(const float* __restrict__ x,
                                                  unsigned char* __restrict__ spk0c) {
  int g = blockIdx.x * 256 + threadIdx.x;
  if (g >= NSTEPS * NB * 1024) return;
  int tb = g >> 10, pix = g & 1023;
  int b = tb & 63;
  unsigned code = 0;
  #pragma unroll
  for (int c = 0; c < 3; ++c) {
    uint32_t i = (uint32_t)((tb * 3 + c) * 1024 + pix);
    uint32_t x0 = 0u, x1 = i;
    threefry2x32(0u, 1u, x0, x1);
    uint32_t bits = x0 ^ x1;
    float u = __uint_as_float((bits >> 9) | 0x3f800000u) - 1.0f;
    float xv = x[(b * 3 + c) * 1024 + pix];
    code |= (u < 2.0f * xv) ? (1u << c) : 0u;
  }
  spk0c[g] = (unsigned char)code;
}

// --- conv1+pool+LIF1 fused over t. block=(b, og of 4 oc), thread=pixel ----
__global__ __launch_bounds__(256) void conv1_lif(const unsigned char* __restrict__ spk0c,
                                                 const double* __restrict__ Weff1,
                                                 unsigned char* __restrict__ spk1) {
  const int b  = blockIdx.x;   // 0..63
  const int og = blockIdx.y;   // 0..7 -> oc = og*4..og*4+3
  __shared__ unsigned char sC[1024];
  const int tid = threadIdx.x;
  const int oh = tid / 14, ow = tid % 14;

  float prev[4] = {0.f, 0.f, 0.f, 0.f};
  for (int t = 0; t < NSTEPS; ++t) {
    __syncthreads();
    if (tid < 64)
      ((uint4*)sC)[tid] = ((const uint4*)(spk0c + (size_t)(t * NB + b) * 1024))[tid];
    __syncthreads();
    if (tid < 196) {
      unsigned char cb[36];
      #pragma unroll
      for (int iy = 0; iy < 6; ++iy)
        #pragma unroll
        for (int ix = 0; ix < 6; ++ix)
          cb[iy * 6 + ix] = sC[(2 * oh + iy) * 32 + 2 * ow + ix];
      double a[4] = {0.0, 0.0, 0.0, 0.0};
      for (int c = 0; c < 3; ++c) {
        const double* w0 = Weff1 + ((og * 4 + 0) * 3 + c) * 36;
        const double* w1 = Weff1 + ((og * 4 + 1) * 3 + c) * 36;
        const double* w2 = Weff1 + ((og * 4 + 2) * 3 + c) * 36;
        const double* w3 = Weff1 + ((og * 4 + 3) * 3 + c) * 36;
        #pragma unroll
        for (int pos = 0; pos < 36; ++pos) {
          double bd = (double)((cb[pos] >> c) & 1);
          a[0] = fma(bd, w0[pos], a[0]);
          a[1] = fma(bd, w1[pos], a[1]);
          a[2] = fma(bd, w2[pos], a[2]);
          a[3] = fma(bd, w3[pos], a[3]);
        }
      }
      #pragma unroll
      for (int j = 0; j < 4; ++j) {
        float cur = (float)(a[j] * 0.25);
        float mem = cur - prev[j];
        bool s = mem > 1.0f;
        spk1[((size_t)(t * NB + b) * 32 + og * 4 + j) * 196 + tid] = s ? 1 : 0;
        prev[j] = s ? 1.0f : 0.0f;
      }
    }
  }
}

// --- pack spk1 bytes -> channel masks mask1[t,b,196] u32 ------------------
__global__ __launch_bounds__(256) void pack1(const unsigned char* __restrict__ spk1,
                                             uint32_t* __restrict__ mask1) {
  const int tb = blockIdx.x;  // t*64+b
  __shared__ unsigned char sF[6272];
  const int tid = threadIdx.x;
  const uint4* src = (const uint4*)(spk1 + (size_t)tb * 6272);
  for (int e = tid; e < 392; e += 256) ((uint4*)sF)[e] = src[e];
  __syncthreads();
  if (tid < 196) {
    uint32_t m = 0;
    #pragma unroll
    for (int c = 0; c < 32; ++c) m |= (uint32_t)(sF[c * 196 + tid] & 1) << c;
    mask1[(size_t)tb * 196 + tid] = m;
  }
}

// --- conv2+pool (t-parallel): cur2[t,b,oc,25] f32 -------------------------
// block=(tc of 8 t, b, og of 4 oc); thread=(th=t-in-chunk, p of 25)
#define C2T 8
__global__ __launch_bounds__(256) void conv2_cur(const uint32_t* __restrict__ mask1,
                                                 const double* __restrict__ Weff2,
                                                 float* __restrict__ cur2) {
  const int tc = blockIdx.x;   // 0..12
  const int b  = blockIdx.y;   // 0..63
  const int og = blockIdx.z;   // 0..15
  __shared__ uint32_t sM[C2T][196];
  const int tid = threadIdx.x;
  const int t0 = tc * C2T;
  const int nt = (NSTEPS - t0 < C2T) ? (NSTEPS - t0) : C2T;

  for (int e = tid; e < nt * 196; e += 256) {
    int tt = e / 196, pp = e % 196;
    sM[tt][pp] = mask1[((size_t)(t0 + tt) * NB + b) * 196 + pp];
  }
  __syncthreads();

  const int th = tid >> 5;     // 0..7
  const int p  = tid & 31;     // 0..31, active < 25
  if (p < 25 && th < nt) {
    const int oh = p / 5, ow = p % 5;
    uint32_t m[36];
    #pragma unroll
    for (int iy = 0; iy < 6; ++iy)
      #pragma unroll
      for (int ix = 0; ix < 6; ++ix)
        m[iy * 6 + ix] = sM[th][(2 * oh + iy) * 14 + 2 * ow + ix];

    double a0 = 0.0, a1 = 0.0, a2 = 0.0, a3 = 0.0;
    const double* Wb = Weff2 + (size_t)og * 4608;  // [c][pos][4]
    for (int c = 0; c < 32; ++c) {
      const double* wc = Wb + c * 144;
      #pragma unroll
      for (int pos = 0; pos < 36; ++pos) {
        double bd = (double)((m[pos] >> c) & 1u);
        a0 = fma(bd, wc[pos * 4 + 0], a0);
        a1 = fma(bd, wc[pos * 4 + 1], a1);
        a2 = fma(bd, wc[pos * 4 + 2], a2);
        a3 = fma(bd, wc[pos * 4 + 3], a3);
      }
    }
    const int t = t0 + th;
    float* dst = cur2 + ((size_t)(t * NB + b) * 64 + og * 4) * 25 + p;
    dst[0]  = (float)(a0 * 0.25);
    dst[25] = (float)(a1 * 0.25);
    dst[50] = (float)(a2 * 0.25);
    dst[75] = (float)(a3 * 0.25);
  }
}

// --- LIF2 scan over t: spk2[t,b,1600] bytes -------------------------------
__global__ __launch_bounds__(256) void scan2(const float* __restrict__ cur2,
                                             unsigned char* __restrict__ spk2) {
  int chain = blockIdx.x * 256 + threadIdx.x;  // (b*64+oc)*25+p
  if (chain >= NB * 64 * 25) return;
  float prev = 0.0f;
  for (int t = 0; t < NSTEPS; ++t) {
    float cur = cur2[(size_t)t * (NB * 1600) + chain];
    float mem = cur - prev;
    bool s = mem > 1.0f;
    spk2[(size_t)t * (NB * 1600) + chain] = s ? 1 : 0;
    prev = s ? 1.0f : 0.0f;
  }
}

// --- FC: cur3[t,b,10] ------------------------------------------------------
__global__ __launch_bounds__(256) void fc_kernel(const unsigned char* __restrict__ spk2,
                                                 const float* __restrict__ W2,
                                                 float* __restrict__ cur3) {
  int gid = blockIdx.x * 256 + threadIdx.x;
  if (gid >= NSTEPS * NB * 10) return;
  int tb = gid / 10, o = gid % 10;
  const unsigned char* s = spk2 + (size_t)tb * 1600;
  const float* w = W2 + o * 1600;
  double acc = 0.0;
  for (int k = 0; k < 1600; ++k) { if (s[k]) acc += (double)w[k]; }
  cur3[gid] = (float)acc;
}

// --- LIF3: out spikes [100,64,10] then mem [100,64,10] --------------------
__global__ __launch_bounds__(256) void lif3_kernel(const float* __restrict__ cur3,
                                                   float* __restrict__ out) {
  int bo = blockIdx.x * 256 + threadIdx.x;
  if (bo >= NB * 10) return;
  float prev = 0.0f;
  for (int t = 0; t < NSTEPS; ++t) {
    float cur = cur3[t * (NB * 10) + bo];
    float mem = cur - prev;
    bool s = mem > 1.0f;
    out[t * (NB * 10) + bo] = s ? 1.0f : 0.0f;
    out[NSTEPS * NB * 10 + t * (NB * 10) + bo] = mem;
    prev = s ? 1.0f : 0.0f;
  }
}

extern "C" void kernel_launch(void* const* d_in, const int* in_sizes, int n_in,
                              void* d_out, int out_size, void* d_ws, size_t ws_size,
                              hipStream_t stream) {
  const float* x    = (const float*)d_in[0];
  const float* W_in = (const float*)d_in[1];
  const float* W_h1 = (const float*)d_in[2];
  const float* W_h2 = (const float*)d_in[3];
  float* out = (float*)d_out;

  unsigned char* ws = (unsigned char*)d_ws;
  // layout (bytes):
  double*        Weff1  = (double*)(ws + 0);              //     27,648
  double*        Weff2  = (double*)(ws + 27648);          //    589,824
  unsigned char* spk0c  = ws + 617472;                    //  6,553,600
  unsigned char* spk1   = ws + 7171072;                   // 40,140,800
  uint32_t*      mask1  = (uint32_t*)(ws + 47311872);     //  5,017,600
  unsigned char* spk2   = ws + 52329472;                  // 10,240,000
  float*         cur3   = (float*)(ws + 62569472);        //    256,000
  // cur2 aliases dead spk0c+spk1 region (conv2 runs after conv1+pack1):
  float*         cur2   = (float*)(ws + 617472);          // 40,960,000 (< 47,311,872)

  weff1_kernel<<<(32 * 3 * 36 + 255) / 256, 256, 0, stream>>>(W_in, Weff1);
  weff2_kernel<<<(16 * 32 * 36 * 4 + 255) / 256, 256, 0, stream>>>(W_h1, Weff2);
  gen_spikes<<<(NSTEPS * NB * 1024) / 256, 256, 0, stream>>>(x, spk0c);
  conv1_lif<<<dim3(64, 8), 256, 0, stream>>>(spk0c, Weff1, spk1);
  pack1<<<NSTEPS * NB, 256, 0, stream>>>(spk1, mask1);
  conv2_cur<<<dim3((NSTEPS + C2T - 1) / C2T, 64, 16), 256, 0, stream>>>(mask1, Weff2, cur2);
  scan2<<<(NB * 64 * 25 + 255) / 256, 256, 0, stream>>>(cur2, spk2);
  fc_kernel<<<(NSTEPS * NB * 10 + 255) / 256, 256, 0, stream>>>(spk2, W_h2, cur3);
  lif3_kernel<<<3, 256, 0, stream>>>(cur3, out);
}

// Round 3
// 713.093 us; speedup vs baseline: 10.4365x; 1.9447x over previous
//
#include <hip/hip_runtime.h>
#include <stdint.h>

// ---------------------------------------------------------------------------
// Conv-SNN, 100 steps, B=64, BETA=0.
// Round 3: everything t-parallel via A/B-bit LIF trick (A=cur>1, B=cur>2),
// bitwise FSM scans for the recurrences, 8-oc f64 FMA blocking, channel-
// silence skip in conv2. f64 accumulation, f32 at reference op boundaries.
// ---------------------------------------------------------------------------

#define NSTEPS 100
#define NB 64

__device__ __forceinline__ uint32_t rotl32(uint32_t v, uint32_t r) {
  return (v << r) | (v >> (32u - r));
}

__device__ __forceinline__ void threefry2x32(uint32_t k0, uint32_t k1,
                                             uint32_t& x0, uint32_t& x1) {
  uint32_t k2 = k0 ^ k1 ^ 0x1BD11BDAu;
  x0 += k0; x1 += k1;
#define TF_R(r) { x0 += x1; x1 = rotl32(x1, r); x1 ^= x0; }
  TF_R(13u) TF_R(15u) TF_R(26u) TF_R(6u)
  x0 += k1; x1 += k2 + 1u;
  TF_R(17u) TF_R(29u) TF_R(16u) TF_R(24u)
  x0 += k2; x1 += k0 + 2u;
  TF_R(13u) TF_R(15u) TF_R(26u) TF_R(6u)
  x0 += k0; x1 += k1 + 3u;
  TF_R(17u) TF_R(29u) TF_R(16u) TF_R(24u)
  x0 += k1; x1 += k2 + 4u;
  TF_R(13u) TF_R(15u) TF_R(26u) TF_R(6u)
  x0 += k2; x1 += k0 + 5u;
#undef TF_R
}

// --- folded-pool weights, conv1 layout [og4][pos36][c3][oj8] --------------
__global__ __launch_bounds__(256) void weff1r_kernel(const float* __restrict__ W_in,
                                                     double* __restrict__ W1R) {
  int e = blockIdx.x * 256 + threadIdx.x;
  if (e >= 4 * 36 * 3 * 8) return;
  int oj = e & 7, c = (e >> 3) % 3, pos = ((e >> 3) / 3) % 36, og = (e >> 3) / 108;
  int oc = og * 8 + oj;
  int iy = pos / 6, ix = pos % 6;
  double w = 0.0;
  for (int dy = 0; dy < 2; ++dy) {
    int ky = iy - dy; if (ky < 0 || ky > 4) continue;
    for (int dx = 0; dx < 2; ++dx) {
      int kx = ix - dx; if (kx < 0 || kx > 4) continue;
      w += (double)W_in[((oc * 3 + c) * 5 + ky) * 5 + kx];
    }
  }
  W1R[e] = w;
}

// conv2 layout [og8][c32][pos36][oj8]
__global__ __launch_bounds__(256) void weff2r_kernel(const float* __restrict__ W_h1,
                                                     double* __restrict__ W2R) {
  int e = blockIdx.x * 256 + threadIdx.x;
  if (e >= 8 * 32 * 36 * 8) return;
  int oj = e & 7, pos = (e >> 3) % 36, c = ((e >> 3) / 36) % 32, og = (e >> 3) / 1152;
  int oc = og * 8 + oj;
  int iy = pos / 6, ix = pos % 6;
  double w = 0.0;
  for (int dy = 0; dy < 2; ++dy) {
    int ky = iy - dy; if (ky < 0 || ky > 4) continue;
    for (int dx = 0; dx < 2; ++dx) {
      int kx = ix - dx; if (kx < 0 || kx > 4) continue;
      w += (double)W_h1[((oc * 32 + c) * 5 + ky) * 5 + kx];
    }
  }
  W2R[e] = w;
}

// --- spike gen: per-pixel 3-bit channel codes [t,b,1024] bytes ------------
__global__ __launch_bounds__(256) void gen_spikes(const float* __restrict__ x,
                                                  unsigned char* __restrict__ spk0c) {
  int g = blockIdx.x * 256 + threadIdx.x;
  if (g >= NSTEPS * NB * 1024) return;
  int tb = g >> 10, pix = g & 1023;
  int b = tb & 63;
  unsigned code = 0;
  #pragma unroll
  for (int c = 0; c < 3; ++c) {
    uint32_t i = (uint32_t)((tb * 3 + c) * 1024 + pix);
    uint32_t x0 = 0u, x1 = i;
    threefry2x32(0u, 1u, x0, x1);
    uint32_t bits = x0 ^ x1;
    float u = __uint_as_float((bits >> 9) | 0x3f800000u) - 1.0f;
    float xv = x[(b * 3 + c) * 1024 + pix];
    code |= (u < 2.0f * xv) ? (1u << c) : 0u;
  }
  spk0c[g] = (unsigned char)code;
}

// --- conv1+pool, t-parallel, emits A/B bytes (8 oc each) ------------------
__global__ __launch_bounds__(256) void conv1_ab(const unsigned char* __restrict__ spk0c,
                                                const double* __restrict__ W1R,
                                                unsigned char* __restrict__ A1,
                                                unsigned char* __restrict__ B1) {
  const int t  = blockIdx.x;   // 0..99
  const int b  = blockIdx.y;   // 0..63
  const int og = blockIdx.z;   // 0..3 -> oc og*8..+7
  __shared__ unsigned char sC[1024];
  const int tid = threadIdx.x;
  if (tid < 64)
    ((uint4*)sC)[tid] = ((const uint4*)(spk0c + (size_t)(t * NB + b) * 1024))[tid];
  __syncthreads();
  if (tid < 196) {
    const int oh = tid / 14, ow = tid % 14;
    const double* Wb = W1R + og * 864;  // 36*3*8
    double a[8] = {0, 0, 0, 0, 0, 0, 0, 0};
    #pragma unroll
    for (int iy = 0; iy < 6; ++iy) {
      #pragma unroll
      for (int ix = 0; ix < 6; ++ix) {
        unsigned code = sC[(2 * oh + iy) * 32 + (2 * ow + ix)];
        const double* wp = Wb + (iy * 6 + ix) * 24;
        #pragma unroll
        for (int c = 0; c < 3; ++c) {
          double bd = (double)((code >> c) & 1u);
          #pragma unroll
          for (int j = 0; j < 8; ++j) a[j] = fma(bd, wp[c * 8 + j], a[j]);
        }
      }
    }
    unsigned ab = 0, bb = 0;
    #pragma unroll
    for (int j = 0; j < 8; ++j) {
      float cur = (float)(a[j] * 0.25);
      if (cur > 1.0f) ab |= 1u << j;
      if (cur > 2.0f) bb |= 1u << j;
    }
    size_t idx = ((size_t)(t * NB + b) * 196 + tid) * 4 + og;
    A1[idx] = (unsigned char)ab;
    B1[idx] = (unsigned char)bb;
  }
}

// --- LIF1 scan: bitwise FSM over t, 32 oc per u32 word --------------------
__global__ __launch_bounds__(256) void scan1(const uint32_t* __restrict__ A1w,
                                             const uint32_t* __restrict__ B1w,
                                             uint32_t* __restrict__ mask1) {
  int chain = blockIdx.x * 256 + threadIdx.x;
  if (chain >= NB * 196) return;
  int b = chain / 196, p = chain % 196;
  uint32_t prev = 0;
  for (int t = 0; t < NSTEPS; ++t) {
    size_t idx = (size_t)(t * NB + b) * 196 + p;
    uint32_t A = A1w[idx], B = B1w[idx];
    uint32_t s = (A & ~prev) | (B & prev);
    mask1[idx] = s;
    prev = s;
  }
}

// --- per-(t,b) channel-presence word --------------------------------------
__global__ __launch_bounds__(256) void chan_any(const uint32_t* __restrict__ mask1,
                                                uint32_t* __restrict__ chanAny) {
  int tb = blockIdx.x * 256 + threadIdx.x;
  if (tb >= NSTEPS * NB) return;
  const uint32_t* m = mask1 + (size_t)tb * 196;
  uint32_t o = 0;
  for (int p = 0; p < 196; ++p) o |= m[p];
  chanAny[tb] = o;
}

// --- conv2+pool, t-parallel, 8 oc per thread, channel skip ----------------
#define C2T 8
__global__ __launch_bounds__(256) void conv2_ab(const uint32_t* __restrict__ mask1,
                                                const uint32_t* __restrict__ chanAny,
                                                const double* __restrict__ W2R,
                                                unsigned char* __restrict__ A2,
                                                unsigned char* __restrict__ B2) {
  const int tc = blockIdx.x;   // 0..12
  const int b  = blockIdx.y;   // 0..63
  const int og = blockIdx.z;   // 0..7 -> oc og*8..+7
  __shared__ uint32_t sM[C2T * 196];
  const int tid = threadIdx.x;
  const int t0 = tc * C2T;
  const int nt = (NSTEPS - t0 < C2T) ? (NSTEPS - t0) : C2T;

  for (int e = tid; e < nt * 196; e += 256) {
    int tt = e / 196, pp = e % 196;
    sM[e] = mask1[((size_t)(t0 + tt) * NB + b) * 196 + pp];
  }
  __syncthreads();

  const int th = tid >> 5;     // 0..7
  const int p  = tid & 31;     // active < 25
  // wave-uniform channel-presence word for this wave's two timesteps
  int wt = t0 + ((tid >> 6) << 1);
  int wt0 = wt < 99 ? wt : 99, wt1 = (wt + 1) < 99 ? (wt + 1) : 99;
  uint32_t skipOr = __builtin_amdgcn_readfirstlane(
      chanAny[wt0 * NB + b] | chanAny[wt1 * NB + b]);

  if (p < 25 && th < nt) {
    const int oh = p / 5, ow = p % 5;
    const uint32_t* base = &sM[th * 196 + (2 * oh) * 14 + 2 * ow];
    double a[8] = {0, 0, 0, 0, 0, 0, 0, 0};
    const double* Wb = W2R + (size_t)og * 9216;  // 32*36*8
    for (int c = 0; c < 32; ++c) {
      if (!((skipOr >> c) & 1u)) continue;
      const double* wc = Wb + c * 288;
      #pragma unroll
      for (int iy = 0; iy < 6; ++iy) {
        #pragma unroll
        for (int ix = 0; ix < 6; ++ix) {
          uint32_t m = base[iy * 14 + ix];
          double bd = (double)((m >> c) & 1u);
          const double* wp = wc + (iy * 6 + ix) * 8;
          #pragma unroll
          for (int j = 0; j < 8; ++j) a[j] = fma(bd, wp[j], a[j]);
        }
      }
    }
    unsigned ab = 0, bb = 0;
    #pragma unroll
    for (int j = 0; j < 8; ++j) {
      float cur = (float)(a[j] * 0.25);
      if (cur > 1.0f) ab |= 1u << j;
      if (cur > 2.0f) bb |= 1u << j;
    }
    const int t = t0 + th;
    size_t idx = ((size_t)(t * NB + b) * 25 + p) * 8 + og;
    A2[idx] = (unsigned char)ab;
    B2[idx] = (unsigned char)bb;
  }
}

// --- LIF2 scan: 64 oc per u64 word ----------------------------------------
__global__ __launch_bounds__(256) void scan2(const uint64_t* __restrict__ A2q,
                                             const uint64_t* __restrict__ B2q,
                                             uint64_t* __restrict__ mask2) {
  int chain = blockIdx.x * 256 + threadIdx.x;
  if (chain >= NB * 25) return;
  int b = chain / 25, p = chain % 25;
  uint64_t prev = 0;
  for (int t = 0; t < NSTEPS; ++t) {
    size_t idx = (size_t)(t * NB + b) * 25 + p;
    uint64_t A = A2q[idx], B = B2q[idx];
    uint64_t s = (A & ~prev) | (B & prev);
    mask2[idx] = s;
    prev = s;
  }
}

// --- FC from packed masks: cur3[t,b,10] -----------------------------------
__global__ __launch_bounds__(256) void fc_kernel(const uint64_t* __restrict__ mask2,
                                                 const float* __restrict__ W2,
                                                 float* __restrict__ cur3) {
  int gid = blockIdx.x * 256 + threadIdx.x;
  if (gid >= NSTEPS * NB * 10) return;
  int tb = gid / 10, o = gid % 10;
  const uint64_t* m = mask2 + (size_t)tb * 25;
  const float* w = W2 + o * 1600;  // flat k = oc*25 + p
  double acc = 0.0;
  for (int p = 0; p < 25; ++p) {
    uint64_t mw = m[p];
    uint32_t lo = (uint32_t)mw, hi = (uint32_t)(mw >> 32);
    #pragma unroll 8
    for (int oc = 0; oc < 32; ++oc) {
      double bd = (double)((lo >> oc) & 1u);
      acc = fma(bd, (double)w[oc * 25 + p], acc);
    }
    #pragma unroll 8
    for (int oc = 32; oc < 64; ++oc) {
      double bd = (double)((hi >> (oc - 32)) & 1u);
      acc = fma(bd, (double)w[oc * 25 + p], acc);
    }
  }
  cur3[gid] = (float)acc;
}

// --- LIF3: out spikes [100,64,10] then mem [100,64,10] --------------------
__global__ __launch_bounds__(256) void lif3_kernel(const float* __restrict__ cur3,
                                                   float* __restrict__ out) {
  int bo = blockIdx.x * 256 + threadIdx.x;
  if (bo >= NB * 10) return;
  float prev = 0.0f;
  for (int t = 0; t < NSTEPS; ++t) {
    float cur = cur3[t * (NB * 10) + bo];
    float mem = cur - prev;
    bool s = mem > 1.0f;
    out[t * (NB * 10) + bo] = s ? 1.0f : 0.0f;
    out[NSTEPS * NB * 10 + t * (NB * 10) + bo] = mem;
    prev = s ? 1.0f : 0.0f;
  }
}

extern "C" void kernel_launch(void* const* d_in, const int* in_sizes, int n_in,
                              void* d_out, int out_size, void* d_ws, size_t ws_size,
                              hipStream_t stream) {
  const float* x    = (const float*)d_in[0];
  const float* W_in = (const float*)d_in[1];
  const float* W_h1 = (const float*)d_in[2];
  const float* W_h2 = (const float*)d_in[3];
  float* out = (float*)d_out;

  unsigned char* ws = (unsigned char*)d_ws;
  double*        W1R     = (double*)(ws + 0);          //     27,648
  double*        W2R     = (double*)(ws + 27648);      //    589,824
  unsigned char* spk0c   = ws + 617472;                //  6,553,600
  unsigned char* A1      = ws + 7171072;               //  5,017,600
  unsigned char* B1      = ws + 12188672;              //  5,017,600
  uint32_t*      mask1   = (uint32_t*)(ws + 17206272); //  5,017,600
  uint32_t*      chanAny = (uint32_t*)(ws + 22223872); //     25,600
  unsigned char* A2      = ws + 22249472;              //  1,280,000
  unsigned char* B2      = ws + 23529472;              //  1,280,000
  uint64_t*      mask2   = (uint64_t*)(ws + 24809472); //  1,280,000
  float*         cur3    = (float*)(ws + 26089472);    //    256,000

  weff1r_kernel<<<14, 256, 0, stream>>>(W_in, W1R);
  weff2r_kernel<<<288, 256, 0, stream>>>(W_h1, W2R);
  gen_spikes<<<NSTEPS * NB * 4, 256, 0, stream>>>(x, spk0c);
  conv1_ab<<<dim3(NSTEPS, NB, 4), 256, 0, stream>>>(spk0c, W1R, A1, B1);
  scan1<<<(NB * 196 + 255) / 256, 256, 0, stream>>>((const uint32_t*)A1,
                                                    (const uint32_t*)B1, mask1);
  chan_any<<<(NSTEPS * NB + 255) / 256, 256, 0, stream>>>(mask1, chanAny);
  conv2_ab<<<dim3(13, NB, 8), 256, 0, stream>>>(mask1, chanAny, W2R, A2, B2);
  scan2<<<(NB * 25 + 255) / 256, 256, 0, stream>>>((const uint64_t*)A2,
                                                   (const uint64_t*)B2, mask2);
  fc_kernel<<<(NSTEPS * NB * 10 + 255) / 256, 256, 0, stream>>>(mask2, W_h2, cur3);
  lif3_kernel<<<3, 256, 0, stream>>>(cur3, out);
}